// Round 10
// baseline (244.344 us; speedup 1.0000x reference)
//
#include <hip/hip_runtime.h>

#define EPS 1e-5f
#define SLOPE 0.01f

typedef short bf16x8 __attribute__((ext_vector_type(8)));
typedef float f32x4 __attribute__((ext_vector_type(4)));

static __device__ __forceinline__ unsigned short f2bf(float f) {
  unsigned u = __float_as_uint(f);
  unsigned r = (u + 0x7FFFu + ((u >> 16) & 1u)) >> 16;
  return (unsigned short)r;
}
#define BFLO(u) __uint_as_float((u) << 16)
#define BFHI(u) __uint_as_float((u) & 0xFFFF0000u)

// ================= CSR build: two-level counting sort =================
// bucket = dst >> 8 (256 nodes/bucket). hist fused with f32->bf16 cvt.
// NBLKB == 256 so hist chunk index == bucket index (bsum[b] folding).

__global__ __launch_bounds__(1024) void hist_cvt_kernel(
    const int* __restrict__ dst, int* __restrict__ hist, int E, int NB,
    int histBlocks, const float* __restrict__ x, unsigned short* __restrict__ xb,
    int total4) {
  extern __shared__ int lh[];
  if ((int)blockIdx.x < histBlocks) {
    for (int i = threadIdx.x; i < NB; i += blockDim.x) lh[i] = 0;
    __syncthreads();
    int E4 = E >> 2;
    int stride = histBlocks * blockDim.x;
    const int4* d4 = (const int4*)dst;
    for (int i = blockIdx.x * blockDim.x + threadIdx.x; i < E4; i += stride) {
      int4 d = d4[i];
      atomicAdd(&lh[((unsigned)d.x) >> 8], 1);
      atomicAdd(&lh[((unsigned)d.y) >> 8], 1);
      atomicAdd(&lh[((unsigned)d.z) >> 8], 1);
      atomicAdd(&lh[((unsigned)d.w) >> 8], 1);
    }
    if (blockIdx.x == 0) {
      for (int i = (E4 << 2) + threadIdx.x; i < E; i += blockDim.x)
        atomicAdd(&lh[((unsigned)dst[i]) >> 8], 1);
    }
    __syncthreads();
    for (int b = threadIdx.x; b < NB; b += blockDim.x)
      hist[(size_t)b * histBlocks + blockIdx.x] = lh[b];
  } else {
    int cb = blockIdx.x - histBlocks;
    int stride = (gridDim.x - histBlocks) * blockDim.x;
    for (int i = cb * blockDim.x + threadIdx.x; i < total4; i += stride) {
      float4 v = reinterpret_cast<const float4*>(x)[i];
      ushort4 o;
      o.x = f2bf(v.x); o.y = f2bf(v.y); o.z = f2bf(v.z); o.w = f2bf(v.w);
      reinterpret_cast<ushort4*>(xb)[i] = o;
    }
  }
}

__global__ void scan_blk(const int* in, int* out, int* bsum, int n) {
  __shared__ int s[256];
  int i = blockIdx.x * 256 + threadIdx.x;
  int v = (i < n) ? in[i] : 0;
  s[threadIdx.x] = v;
  __syncthreads();
  for (int off = 1; off < 256; off <<= 1) {
    int t = (threadIdx.x >= off) ? s[threadIdx.x - off] : 0;
    __syncthreads();
    s[threadIdx.x] += t;
    __syncthreads();
  }
  if (i < n) out[i] = s[threadIdx.x] - v;
  if (threadIdx.x == 255) bsum[blockIdx.x] = s[255];
}

__global__ void scan_top(int* bsum, int nb) {
  __shared__ int s[512];
  int tid = threadIdx.x;
  int v = (tid < nb) ? bsum[tid] : 0;
  s[tid] = v;
  __syncthreads();
  for (int off = 1; off < 512; off <<= 1) {
    int t = (tid >= off) ? s[tid - off] : 0;
    __syncthreads();
    s[tid] += t;
    __syncthreads();
  }
  if (tid < nb) bsum[tid] = s[tid] - v;
}

// scatter: histS[b*256+blk] + bsum[b] = global base of this block's segment of bucket b
__global__ __launch_bounds__(1024) void scatter_kernel(
    const int* __restrict__ src, const int* __restrict__ dst,
    const int* __restrict__ histS, const int* __restrict__ bsum,
    unsigned* __restrict__ binned, int E, int NB) {
  extern __shared__ int cur[];
  for (int b = threadIdx.x; b < NB; b += blockDim.x)
    cur[b] = histS[(size_t)b * gridDim.x + blockIdx.x] + bsum[b];
  __syncthreads();
  int E4 = E >> 2;
  int stride = gridDim.x * blockDim.x;
  const int4* d4 = (const int4*)dst;
  const int4* s4 = (const int4*)src;
  for (int i = blockIdx.x * blockDim.x + threadIdx.x; i < E4; i += stride) {
    int4 d = d4[i];
    int4 s = s4[i];
    int b0 = ((unsigned)d.x) >> 8;
    binned[atomicAdd(&cur[b0], 1)] = (unsigned)s.x | (((unsigned)d.x & 255u) << 20);
    int b1 = ((unsigned)d.y) >> 8;
    binned[atomicAdd(&cur[b1], 1)] = (unsigned)s.y | (((unsigned)d.y & 255u) << 20);
    int b2 = ((unsigned)d.z) >> 8;
    binned[atomicAdd(&cur[b2], 1)] = (unsigned)s.z | (((unsigned)d.z & 255u) << 20);
    int b3 = ((unsigned)d.w) >> 8;
    binned[atomicAdd(&cur[b3], 1)] = (unsigned)s.w | (((unsigned)d.w & 255u) << 20);
  }
  if (blockIdx.x == 0) {
    for (int i = (E4 << 2) + threadIdx.x; i < E; i += blockDim.x) {
      int d = dst[i];
      int b = ((unsigned)d) >> 8;
      binned[atomicAdd(&cur[b], 1)] = (unsigned)src[i] | (((unsigned)d & 255u) << 20);
    }
  }
}

__global__ __launch_bounds__(256) void fine_kernel(
    const unsigned* __restrict__ binned, const int* __restrict__ histS,
    const int* __restrict__ bsum,
    int* __restrict__ rowptr, int* __restrict__ col, int E, int NB, int NBLKB, int N) {
  __shared__ int ldeg[256];
  __shared__ int lcur[256];
  __shared__ int ss[256];
  int b = blockIdx.x;
  int tid = threadIdx.x;
  int seg_s = histS[(size_t)b * NBLKB] + bsum[b];
  int seg_e = (b + 1 < NB) ? (histS[(size_t)(b + 1) * NBLKB] + bsum[b + 1]) : E;
  ldeg[tid] = 0;
  __syncthreads();
  for (int i = seg_s + tid; i < seg_e; i += 256)
    atomicAdd(&ldeg[(binned[i] >> 20) & 255u], 1);
  __syncthreads();
  int d = ldeg[tid];
  ss[tid] = d;
  __syncthreads();
  for (int off = 1; off < 256; off <<= 1) {
    int t = (tid >= off) ? ss[tid - off] : 0;
    __syncthreads();
    ss[tid] += t;
    __syncthreads();
  }
  int base = seg_s + ss[tid] - d;
  lcur[tid] = base;
  int node = (b << 8) + tid;
  if (node < N) rowptr[node] = base;
  if (b == NB - 1 && tid == 0) rowptr[N] = E;  // sentinel
  __syncthreads();
  for (int i = seg_s + tid; i < seg_e; i += 256) {
    unsigned v = binned[i];
    int pos = atomicAdd(&lcur[(v >> 20) & 255u], 1);
    col[pos] = (int)(v & 0xFFFFFu);
  }
}

// ========== FUSED layer kernel: gather-mean (LDS) + dual MFMA matvec ==========
// One 64-row super-tile per block (grid = ceil(N/64)), 256 threads.
// Phase 1: 8 lanes/node x 32 nodes x 2 batches gather neighbors -> mean ->
//          LDS X[64][65] f32 (padded, 2-way max bank alias).
// Phase 2: 4 waves x 16 rows: A-self frags from global, A-neigh frags from
//          LDS (f32->bf16, same rounding as the old hmb path), W in regs.
// B-frag loads placed after the barrier to keep phase-1 VGPR live range low.

#define XLD 65  // f32 row stride in LDS

__global__ __launch_bounds__(256, 4) void fused_layer(
    const unsigned short* __restrict__ hb,   // [n][64] bf16 node features
    const int* __restrict__ rowptr, const int* __restrict__ col,
    const float* __restrict__ Wself, const float* __restrict__ Wneigh,
    const float* __restrict__ bias,
    unsigned short* __restrict__ zb, float* __restrict__ partial, int n) {
  __shared__ float X[64 * XLD];
  __shared__ float sred[128];
  int tid = threadIdx.x;
  int rowbase = blockIdx.x * 64;

  // ---- phase 1: gather + mean into LDS ----
  int si = tid & 7;        // feature slice: 8 f32 feats at si*8
  int gi = tid >> 3;       // node sub-index 0..31
  #pragma unroll
  for (int b = 0; b < 2; ++b) {
    int node = rowbase + b * 32 + gi;
    float a0 = 0.f, a1 = 0.f, a2 = 0.f, a3 = 0.f;
    float a4 = 0.f, a5 = 0.f, a6 = 0.f, a7 = 0.f;
    int deg = 0;
    if (node < n) {
      int beg = rowptr[node];
      int end = rowptr[node + 1];
      deg = end - beg;
      int e = beg;
      for (; e + 4 <= end; e += 4) {
        int i0 = col[e], i1 = col[e + 1], i2 = col[e + 2], i3 = col[e + 3];
        uint4 u0 = *reinterpret_cast<const uint4*>(&hb[(size_t)i0 * 64 + si * 8]);
        uint4 u1 = *reinterpret_cast<const uint4*>(&hb[(size_t)i1 * 64 + si * 8]);
        uint4 u2 = *reinterpret_cast<const uint4*>(&hb[(size_t)i2 * 64 + si * 8]);
        uint4 u3 = *reinterpret_cast<const uint4*>(&hb[(size_t)i3 * 64 + si * 8]);
        a0 += BFLO(u0.x) + BFLO(u1.x) + BFLO(u2.x) + BFLO(u3.x);
        a1 += BFHI(u0.x) + BFHI(u1.x) + BFHI(u2.x) + BFHI(u3.x);
        a2 += BFLO(u0.y) + BFLO(u1.y) + BFLO(u2.y) + BFLO(u3.y);
        a3 += BFHI(u0.y) + BFHI(u1.y) + BFHI(u2.y) + BFHI(u3.y);
        a4 += BFLO(u0.z) + BFLO(u1.z) + BFLO(u2.z) + BFLO(u3.z);
        a5 += BFHI(u0.z) + BFHI(u1.z) + BFHI(u2.z) + BFHI(u3.z);
        a6 += BFLO(u0.w) + BFLO(u1.w) + BFLO(u2.w) + BFLO(u3.w);
        a7 += BFHI(u0.w) + BFHI(u1.w) + BFHI(u2.w) + BFHI(u3.w);
      }
      for (; e < end; ++e) {
        uint4 u = *reinterpret_cast<const uint4*>(&hb[(size_t)col[e] * 64 + si * 8]);
        a0 += BFLO(u.x); a1 += BFHI(u.x);
        a2 += BFLO(u.y); a3 += BFHI(u.y);
        a4 += BFLO(u.z); a5 += BFHI(u.z);
        a6 += BFLO(u.w); a7 += BFHI(u.w);
      }
    }
    float inv = 1.0f / (float)(deg > 0 ? deg : 1);
    float* xr = &X[(b * 32 + gi) * XLD + si * 8];
    xr[0] = a0 * inv; xr[1] = a1 * inv; xr[2] = a2 * inv; xr[3] = a3 * inv;
    xr[4] = a4 * inv; xr[5] = a5 * inv; xr[6] = a6 * inv; xr[7] = a7 * inv;
  }
  if (tid < 128) sred[tid] = 0.f;
  __syncthreads();

  // ---- phase 2: MFMA ----
  int lane = tid & 63;
  int w = tid >> 6;
  int l15 = lane & 15;
  int g = lane >> 4;

  // B fragments (loaded after barrier; 64 VGPR live only in this phase)
  bf16x8 B[4][4];
  #pragma unroll
  for (int t = 0; t < 4; ++t) {
    #pragma unroll
    for (int s = 0; s < 4; ++s) {
      const float* base = (s < 2 ? Wself : Wneigh) + (t * 16 + l15) * 64 + (s & 1) * 32 + g * 8;
      float4 w0 = *reinterpret_cast<const float4*>(base);
      float4 w1 = *reinterpret_cast<const float4*>(base + 4);
      bf16x8 bb;
      bb[0] = (short)f2bf(w0.x); bb[1] = (short)f2bf(w0.y);
      bb[2] = (short)f2bf(w0.z); bb[3] = (short)f2bf(w0.w);
      bb[4] = (short)f2bf(w1.x); bb[5] = (short)f2bf(w1.y);
      bb[6] = (short)f2bf(w1.z); bb[7] = (short)f2bf(w1.w);
      B[t][s] = bb;
    }
  }
  float bv[4];
  #pragma unroll
  for (int t = 0; t < 4; ++t) bv[t] = bias[t * 16 + l15];

  int r0 = rowbase + w * 16 + l15;
  // A-self frags from global
  uint4 a0[2];
  if (r0 < n) {
    const uint4* pa0 = reinterpret_cast<const uint4*>(hb + (size_t)r0 * 64);
    a0[0] = pa0[g]; a0[1] = pa0[4 + g];
  } else {
    a0[0] = a0[1] = make_uint4(0u, 0u, 0u, 0u);
  }
  // A-neigh frags from LDS (f32 -> bf16)
  const float* xr = &X[(w * 16 + l15) * XLD];
  bf16x8 a1[2];
  #pragma unroll
  for (int h = 0; h < 2; ++h) {
    const float* p = xr + h * 32 + g * 8;
    bf16x8 v;
    #pragma unroll
    for (int j = 0; j < 8; ++j) v[j] = (short)f2bf(p[j]);
    a1[h] = v;
  }

  f32x4 acc[4] = {};
  #pragma unroll
  for (int s = 0; s < 4; ++s) {
    bf16x8 af = (s < 2) ? *reinterpret_cast<bf16x8*>(&a0[s])
                        : a1[s - 2];
    #pragma unroll
    for (int t = 0; t < 4; ++t)
      acc[t] = __builtin_amdgcn_mfma_f32_16x16x32_bf16(af, B[t][s], acc[t], 0, 0, 0);
  }

  float ps[4] = {0.f, 0.f, 0.f, 0.f};
  float pq[4] = {0.f, 0.f, 0.f, 0.f};
  #pragma unroll
  for (int t = 0; t < 4; ++t) {
    #pragma unroll
    for (int i = 0; i < 4; ++i) {
      int gr = rowbase + w * 16 + g * 4 + i;
      if (gr < n) {
        float v = acc[t][i] + bv[t];
        zb[(size_t)gr * 64 + t * 16 + l15] = f2bf(v);
        ps[t] += v;
        pq[t] += v * v;
      }
    }
  }

  #pragma unroll
  for (int t = 0; t < 4; ++t) {
    ps[t] += __shfl_xor(ps[t], 16); ps[t] += __shfl_xor(ps[t], 32);
    pq[t] += __shfl_xor(pq[t], 16); pq[t] += __shfl_xor(pq[t], 32);
  }
  if (lane < 16) {
    #pragma unroll
    for (int t = 0; t < 4; ++t) {
      atomicAdd(&sred[t * 16 + l15], ps[t]);
      atomicAdd(&sred[64 + t * 16 + l15], pq[t]);
    }
  }
  __syncthreads();
  if (tid < 128) partial[(size_t)blockIdx.x * 128 + tid] = sred[tid];
}

// reduce partials -> BN coefficients sc/sh directly.  grid = 64
__global__ __launch_bounds__(256) void reduce_coef(
    const float* __restrict__ partial, const float* __restrict__ gamma,
    const float* __restrict__ beta, float* __restrict__ coef, int nblk, float invN) {
  int f = blockIdx.x;
  float s = 0.f, q = 0.f;
  for (int j = threadIdx.x; j < nblk; j += 256) {
    s += partial[(size_t)j * 128 + f];
    q += partial[(size_t)j * 128 + 64 + f];
  }
  #pragma unroll
  for (int o = 1; o < 64; o <<= 1) {
    s += __shfl_xor(s, o);
    q += __shfl_xor(q, o);
  }
  __shared__ float rs[4], rq[4];
  if ((threadIdx.x & 63) == 0) {
    rs[threadIdx.x >> 6] = s;
    rq[threadIdx.x >> 6] = q;
  }
  __syncthreads();
  if (threadIdx.x == 0) {
    float S = rs[0] + rs[1] + rs[2] + rs[3];
    float Q = rq[0] + rq[1] + rq[2] + rq[3];
    float mu = S * invN;
    float var = Q * invN - mu * mu;
    float sc = rsqrtf(var + EPS) * gamma[f];
    coef[f] = sc;
    coef[64 + f] = beta[f] - mu * sc;
  }
}

// ---------------- BN (apply) + leaky relu, bf16 z input ----------------

__global__ void bn_bf16_kernel(const unsigned short* __restrict__ zb,
                               const float* __restrict__ coef,
                               unsigned short* __restrict__ out, int n) {
  __shared__ float sc[64];
  __shared__ float sh[64];
  if (threadIdx.x < 64) {
    sc[threadIdx.x] = coef[threadIdx.x];
    sh[threadIdx.x] = coef[64 + threadIdx.x];
  }
  __syncthreads();
  int total = n * 16;
  int stride = gridDim.x * blockDim.x;
  for (int idx = blockIdx.x * blockDim.x + threadIdx.x; idx < total; idx += stride) {
    int f0 = (idx & 15) * 4;
    uint2 u = reinterpret_cast<const uint2*>(zb)[idx];
    float t;
    ushort4 o;
    t = BFLO(u.x) * sc[f0 + 0] + sh[f0 + 0]; o.x = f2bf(t > 0.f ? t : SLOPE * t);
    t = BFHI(u.x) * sc[f0 + 1] + sh[f0 + 1]; o.y = f2bf(t > 0.f ? t : SLOPE * t);
    t = BFLO(u.y) * sc[f0 + 2] + sh[f0 + 2]; o.z = f2bf(t > 0.f ? t : SLOPE * t);
    t = BFHI(u.y) * sc[f0 + 3] + sh[f0 + 3]; o.w = f2bf(t > 0.f ? t : SLOPE * t);
    reinterpret_cast<ushort4*>(out)[idx] = o;
  }
}

__global__ void bn_f32_kernel(const unsigned short* __restrict__ zb,
                              const float* __restrict__ coef,
                              float* __restrict__ out, int n) {
  __shared__ float sc[64];
  __shared__ float sh[64];
  if (threadIdx.x < 64) {
    sc[threadIdx.x] = coef[threadIdx.x];
    sh[threadIdx.x] = coef[64 + threadIdx.x];
  }
  __syncthreads();
  int total = n * 16;
  int stride = gridDim.x * blockDim.x;
  for (int idx = blockIdx.x * blockDim.x + threadIdx.x; idx < total; idx += stride) {
    int f0 = (idx & 15) * 4;
    uint2 u = reinterpret_cast<const uint2*>(zb)[idx];
    float4 o;
    float t;
    t = BFLO(u.x) * sc[f0 + 0] + sh[f0 + 0]; o.x = t > 0.f ? t : SLOPE * t;
    t = BFHI(u.x) * sc[f0 + 1] + sh[f0 + 1]; o.y = t > 0.f ? t : SLOPE * t;
    t = BFLO(u.y) * sc[f0 + 2] + sh[f0 + 2]; o.z = t > 0.f ? t : SLOPE * t;
    t = BFHI(u.y) * sc[f0 + 3] + sh[f0 + 3]; o.w = t > 0.f ? t : SLOPE * t;
    reinterpret_cast<float4*>(out)[idx] = o;
  }
}

// ---------------- launch ----------------

extern "C" void kernel_launch(void* const* d_in, const int* in_sizes, int n_in,
                              void* d_out, int out_size, void* d_ws, size_t ws_size,
                              hipStream_t stream) {
  const float* x  = (const float*)d_in[0];
  const int* ei   = (const int*)d_in[1];
  const float* Ws1 = (const float*)d_in[2];
  const float* Wn1 = (const float*)d_in[3];
  const float* b1  = (const float*)d_in[4];
  const float* g1  = (const float*)d_in[5];
  const float* be1 = (const float*)d_in[6];
  const float* Ws2 = (const float*)d_in[7];
  const float* Wn2 = (const float*)d_in[8];
  const float* b2  = (const float*)d_in[9];
  const float* g2  = (const float*)d_in[10];
  const float* be2 = (const float*)d_in[11];
  float* out = (float*)d_out;

  int N = in_sizes[0] / 64;
  int E = in_sizes[1] / 2;
  const int* src = ei;
  const int* dst = ei + E;

  int NB = (N + 255) >> 8;      // buckets of 256 nodes
  const int NBLKB = 256;        // hist/scatter parallel blocks (MUST stay 256)
  int M = NB * NBLKB;

  int NSUPER = (N + 63) / 64;   // fused-layer blocks (64 rows each)

  char* ws = (char*)d_ws;
  float* coef1 = (float*)ws;             // 128 (sc|sh, overwritten each call)
  float* coef2 = coef1 + 128;            // 128
  size_t off = 1024;
  auto take = [&](size_t bytes) {
    void* p = ws + off;
    off = (off + bytes + 255) & ~(size_t)255;
    return p;
  };
  int* hist   = (int*)take((size_t)M * 4);
  int* bsum   = (int*)take(512 * 4);
  int* rowptr = (int*)take((size_t)(N + 1) * 4);
  unsigned* binned = (unsigned*)take((size_t)E * 4);
  int* col    = (int*)take((size_t)E * 4);
  unsigned short* xb  = (unsigned short*)take((size_t)N * 64 * 2);
  unsigned short* h1b = (unsigned short*)take((size_t)N * 64 * 2);
  unsigned short* zb  = (unsigned short*)take((size_t)N * 64 * 2);
  float* partial = (float*)take((size_t)NSUPER * 128 * 4);

  // CSR build + cvt (fused)
  hist_cvt_kernel<<<NBLKB + 128, 1024, NB * 4, stream>>>(dst, hist, E, NB, NBLKB,
                                                         x, xb, N * 16);
  int nb1 = (M + 255) / 256;  // == NB, one scan chunk per bucket
  scan_blk<<<nb1, 256, 0, stream>>>(hist, hist, bsum, M);
  scan_top<<<1, 512, 0, stream>>>(bsum, nb1);
  scatter_kernel<<<NBLKB, 1024, NB * 4, stream>>>(src, dst, hist, bsum, binned, E, NB);
  fine_kernel<<<NB, 256, 0, stream>>>(binned, hist, bsum, rowptr, col, E, NB, NBLKB, N);

  float invN = 1.0f / (float)N;

  // layer 1 (fused gather+GEMM)
  fused_layer<<<NSUPER, 256, 0, stream>>>(xb, rowptr, col, Ws1, Wn1, b1, zb, partial, N);
  reduce_coef<<<64, 256, 0, stream>>>(partial, g1, be1, coef1, NSUPER, invN);
  bn_bf16_kernel<<<2048, 256, 0, stream>>>(zb, coef1, h1b, N);

  // layer 2
  fused_layer<<<NSUPER, 256, 0, stream>>>(h1b, rowptr, col, Ws2, Wn2, b2, zb, partial, N);
  reduce_coef<<<64, 256, 0, stream>>>(partial, g2, be2, coef2, NSUPER, invN);
  bn_f32_kernel<<<2048, 256, 0, stream>>>(zb, coef2, out, N);
}

// Round 11
// 182.425 us; speedup vs baseline: 1.3394x; 1.3394x over previous
//
#include <hip/hip_runtime.h>

#define EPS 1e-5f
#define SLOPE 0.01f

typedef short bf16x8 __attribute__((ext_vector_type(8)));
typedef float f32x4 __attribute__((ext_vector_type(4)));

static __device__ __forceinline__ unsigned short f2bf(float f) {
  unsigned u = __float_as_uint(f);
  unsigned r = (u + 0x7FFFu + ((u >> 16) & 1u)) >> 16;
  return (unsigned short)r;
}
#define BFLO(u) __uint_as_float((u) << 16)
#define BFHI(u) __uint_as_float((u) & 0xFFFF0000u)

// ================= CSR build: two-level counting sort =================
// bucket = dst >> 8 (256 nodes/bucket). hist fused with f32->bf16 cvt.
// NBLKB == 256 so hist chunk index == bucket index (bsum[b] folding).

__global__ __launch_bounds__(1024) void hist_cvt_kernel(
    const int* __restrict__ dst, int* __restrict__ hist, int E, int NB,
    int histBlocks, const float* __restrict__ x, unsigned short* __restrict__ xb,
    int total4) {
  extern __shared__ int lh[];
  if ((int)blockIdx.x < histBlocks) {
    for (int i = threadIdx.x; i < NB; i += blockDim.x) lh[i] = 0;
    __syncthreads();
    int E4 = E >> 2;
    int stride = histBlocks * blockDim.x;
    const int4* d4 = (const int4*)dst;
    for (int i = blockIdx.x * blockDim.x + threadIdx.x; i < E4; i += stride) {
      int4 d = d4[i];
      atomicAdd(&lh[((unsigned)d.x) >> 8], 1);
      atomicAdd(&lh[((unsigned)d.y) >> 8], 1);
      atomicAdd(&lh[((unsigned)d.z) >> 8], 1);
      atomicAdd(&lh[((unsigned)d.w) >> 8], 1);
    }
    if (blockIdx.x == 0) {
      for (int i = (E4 << 2) + threadIdx.x; i < E; i += blockDim.x)
        atomicAdd(&lh[((unsigned)dst[i]) >> 8], 1);
    }
    __syncthreads();
    for (int b = threadIdx.x; b < NB; b += blockDim.x)
      hist[(size_t)b * histBlocks + blockIdx.x] = lh[b];
  } else {
    int cb = blockIdx.x - histBlocks;
    int stride = (gridDim.x - histBlocks) * blockDim.x;
    for (int i = cb * blockDim.x + threadIdx.x; i < total4; i += stride) {
      float4 v = reinterpret_cast<const float4*>(x)[i];
      ushort4 o;
      o.x = f2bf(v.x); o.y = f2bf(v.y); o.z = f2bf(v.z); o.w = f2bf(v.w);
      reinterpret_cast<ushort4*>(xb)[i] = o;
    }
  }
}

__global__ void scan_blk(const int* in, int* out, int* bsum, int n) {
  __shared__ int s[256];
  int i = blockIdx.x * 256 + threadIdx.x;
  int v = (i < n) ? in[i] : 0;
  s[threadIdx.x] = v;
  __syncthreads();
  for (int off = 1; off < 256; off <<= 1) {
    int t = (threadIdx.x >= off) ? s[threadIdx.x - off] : 0;
    __syncthreads();
    s[threadIdx.x] += t;
    __syncthreads();
  }
  if (i < n) out[i] = s[threadIdx.x] - v;
  if (threadIdx.x == 255) bsum[blockIdx.x] = s[255];
}

__global__ void scan_top(int* bsum, int nb) {
  __shared__ int s[512];
  int tid = threadIdx.x;
  int v = (tid < nb) ? bsum[tid] : 0;
  s[tid] = v;
  __syncthreads();
  for (int off = 1; off < 512; off <<= 1) {
    int t = (tid >= off) ? s[tid - off] : 0;
    __syncthreads();
    s[tid] += t;
    __syncthreads();
  }
  if (tid < nb) bsum[tid] = s[tid] - v;
}

// scatter: histS[b*256+blk] + bsum[b] = global base of this block's segment of bucket b
__global__ __launch_bounds__(1024) void scatter_kernel(
    const int* __restrict__ src, const int* __restrict__ dst,
    const int* __restrict__ histS, const int* __restrict__ bsum,
    unsigned* __restrict__ binned, int E, int NB) {
  extern __shared__ int cur[];
  for (int b = threadIdx.x; b < NB; b += blockDim.x)
    cur[b] = histS[(size_t)b * gridDim.x + blockIdx.x] + bsum[b];
  __syncthreads();
  int E4 = E >> 2;
  int stride = gridDim.x * blockDim.x;
  const int4* d4 = (const int4*)dst;
  const int4* s4 = (const int4*)src;
  for (int i = blockIdx.x * blockDim.x + threadIdx.x; i < E4; i += stride) {
    int4 d = d4[i];
    int4 s = s4[i];
    int b0 = ((unsigned)d.x) >> 8;
    binned[atomicAdd(&cur[b0], 1)] = (unsigned)s.x | (((unsigned)d.x & 255u) << 20);
    int b1 = ((unsigned)d.y) >> 8;
    binned[atomicAdd(&cur[b1], 1)] = (unsigned)s.y | (((unsigned)d.y & 255u) << 20);
    int b2 = ((unsigned)d.z) >> 8;
    binned[atomicAdd(&cur[b2], 1)] = (unsigned)s.z | (((unsigned)d.z & 255u) << 20);
    int b3 = ((unsigned)d.w) >> 8;
    binned[atomicAdd(&cur[b3], 1)] = (unsigned)s.w | (((unsigned)d.w & 255u) << 20);
  }
  if (blockIdx.x == 0) {
    for (int i = (E4 << 2) + threadIdx.x; i < E; i += blockDim.x) {
      int d = dst[i];
      int b = ((unsigned)d) >> 8;
      binned[atomicAdd(&cur[b], 1)] = (unsigned)src[i] | (((unsigned)d & 255u) << 20);
    }
  }
}

__global__ __launch_bounds__(256) void fine_kernel(
    const unsigned* __restrict__ binned, const int* __restrict__ histS,
    const int* __restrict__ bsum,
    int* __restrict__ rowptr, int* __restrict__ col, int E, int NB, int NBLKB, int N) {
  __shared__ int ldeg[256];
  __shared__ int lcur[256];
  __shared__ int ss[256];
  int b = blockIdx.x;
  int tid = threadIdx.x;
  int seg_s = histS[(size_t)b * NBLKB] + bsum[b];
  int seg_e = (b + 1 < NB) ? (histS[(size_t)(b + 1) * NBLKB] + bsum[b + 1]) : E;
  ldeg[tid] = 0;
  __syncthreads();
  for (int i = seg_s + tid; i < seg_e; i += 256)
    atomicAdd(&ldeg[(binned[i] >> 20) & 255u], 1);
  __syncthreads();
  int d = ldeg[tid];
  ss[tid] = d;
  __syncthreads();
  for (int off = 1; off < 256; off <<= 1) {
    int t = (tid >= off) ? ss[tid - off] : 0;
    __syncthreads();
    ss[tid] += t;
    __syncthreads();
  }
  int base = seg_s + ss[tid] - d;
  lcur[tid] = base;
  int node = (b << 8) + tid;
  if (node < N) rowptr[node] = base;
  if (b == NB - 1 && tid == 0) rowptr[N] = E;  // sentinel
  __syncthreads();
  for (int i = seg_s + tid; i < seg_e; i += 256) {
    unsigned v = binned[i];
    int pos = atomicAdd(&lcur[(v >> 20) & 255u], 1);
    col[pos] = (int)(v & 0xFFFFFu);
  }
}

// ------- neighbor mean: 8 threads/node, uint4 gathers, unroll-4 -------
// BN=true: apply y = leaky(sc[f]*v + sh[f]) per gathered element (consumer-side
// fusion of the layer-1 BN). __launch_bounds__(256,8) pins VGPR<=64 (occupancy
// cliff at 64 per m69; round 8's unroll-8 crossed it and regressed).

template <bool BN>
__global__ __launch_bounds__(256, 8) void agg_kernel(
    const unsigned short* __restrict__ hb, const int* __restrict__ rowptr,
    const int* __restrict__ col, const float* __restrict__ coef,
    unsigned short* __restrict__ hm, int n) {
  int t = blockIdx.x * 256 + threadIdx.x;
  int node = t >> 3;
  int fo = (t & 7) * 8;  // 8 features per lane
  if (node >= n) return;
  float scr[8], shr[8];
  if (BN) {
    #pragma unroll
    for (int j = 0; j < 8; ++j) {
      scr[j] = coef[fo + j];
      shr[j] = coef[64 + fo + j];
    }
  }
  int beg = rowptr[node];
  int end = rowptr[node + 1];
  float s0 = 0.f, s1 = 0.f, s2 = 0.f, s3 = 0.f;
  float s4 = 0.f, s5 = 0.f, s6 = 0.f, s7 = 0.f;
  auto acc1 = [&](uint4 u) {
    float v0 = BFLO(u.x), v1 = BFHI(u.x), v2 = BFLO(u.y), v3 = BFHI(u.y);
    float v4 = BFLO(u.z), v5 = BFHI(u.z), v6 = BFLO(u.w), v7 = BFHI(u.w);
    if (BN) {
      v0 = v0 * scr[0] + shr[0]; v0 = v0 > 0.f ? v0 : SLOPE * v0;
      v1 = v1 * scr[1] + shr[1]; v1 = v1 > 0.f ? v1 : SLOPE * v1;
      v2 = v2 * scr[2] + shr[2]; v2 = v2 > 0.f ? v2 : SLOPE * v2;
      v3 = v3 * scr[3] + shr[3]; v3 = v3 > 0.f ? v3 : SLOPE * v3;
      v4 = v4 * scr[4] + shr[4]; v4 = v4 > 0.f ? v4 : SLOPE * v4;
      v5 = v5 * scr[5] + shr[5]; v5 = v5 > 0.f ? v5 : SLOPE * v5;
      v6 = v6 * scr[6] + shr[6]; v6 = v6 > 0.f ? v6 : SLOPE * v6;
      v7 = v7 * scr[7] + shr[7]; v7 = v7 > 0.f ? v7 : SLOPE * v7;
    }
    s0 += v0; s1 += v1; s2 += v2; s3 += v3;
    s4 += v4; s5 += v5; s6 += v6; s7 += v7;
  };
  int e = beg;
  for (; e + 4 <= end; e += 4) {
    int i0 = col[e], i1 = col[e + 1], i2 = col[e + 2], i3 = col[e + 3];
    uint4 u0 = *reinterpret_cast<const uint4*>(&hb[(size_t)i0 * 64 + fo]);
    uint4 u1 = *reinterpret_cast<const uint4*>(&hb[(size_t)i1 * 64 + fo]);
    uint4 u2 = *reinterpret_cast<const uint4*>(&hb[(size_t)i2 * 64 + fo]);
    uint4 u3 = *reinterpret_cast<const uint4*>(&hb[(size_t)i3 * 64 + fo]);
    acc1(u0); acc1(u1); acc1(u2); acc1(u3);
  }
  for (; e < end; ++e) {
    uint4 u = *reinterpret_cast<const uint4*>(&hb[(size_t)col[e] * 64 + fo]);
    acc1(u);
  }
  int deg = end - beg;
  float inv = 1.0f / (float)(deg > 0 ? deg : 1);
  uint4 o;
  o.x = (unsigned)f2bf(s0 * inv) | ((unsigned)f2bf(s1 * inv) << 16);
  o.y = (unsigned)f2bf(s2 * inv) | ((unsigned)f2bf(s3 * inv) << 16);
  o.z = (unsigned)f2bf(s4 * inv) | ((unsigned)f2bf(s5 * inv) << 16);
  o.w = (unsigned)f2bf(s6 * inv) | ((unsigned)f2bf(s7 * inv) << 16);
  *reinterpret_cast<uint4*>(&hm[(size_t)node * 64 + fo]) = o;
}

// ========== streaming MFMA GEMM, bf16 z output ==========
// BN=true: A0 rows come from zb with leaky(sc*v+sh) applied at frag build
// (self-term of layer 2). zb read/write is row-disjoint per wave -> in-place ok.

template <bool BN>
__global__ __launch_bounds__(256) void gemm_stream(
    const unsigned short* __restrict__ A0,
    const unsigned short* __restrict__ A1,
    const float* __restrict__ Wself, const float* __restrict__ Wneigh,
    const float* __restrict__ bias, const float* __restrict__ coef,
    unsigned short* __restrict__ zb, float* __restrict__ partial, int n, int ntiles) {
  int tid = threadIdx.x;
  int lane = tid & 63;
  int w = tid >> 6;
  int l15 = lane & 15;
  int g = lane >> 4;

  bf16x8 B[4][4];
  #pragma unroll
  for (int t = 0; t < 4; ++t) {
    #pragma unroll
    for (int s = 0; s < 4; ++s) {
      const float* base = (s < 2 ? Wself : Wneigh) + (t * 16 + l15) * 64 + (s & 1) * 32 + g * 8;
      float4 w0 = *reinterpret_cast<const float4*>(base);
      float4 w1 = *reinterpret_cast<const float4*>(base + 4);
      bf16x8 b;
      b[0] = (short)f2bf(w0.x); b[1] = (short)f2bf(w0.y);
      b[2] = (short)f2bf(w0.z); b[3] = (short)f2bf(w0.w);
      b[4] = (short)f2bf(w1.x); b[5] = (short)f2bf(w1.y);
      b[6] = (short)f2bf(w1.z); b[7] = (short)f2bf(w1.w);
      B[t][s] = b;
    }
  }
  float bv[4];
  #pragma unroll
  for (int t = 0; t < 4; ++t) bv[t] = bias[t * 16 + l15];

  // per-lane BN coef for A0 frags: features g*8..+7 (k-half 0) and 32+g*8..+7
  float scA[2][8], shA[2][8];
  if (BN) {
    #pragma unroll
    for (int h = 0; h < 2; ++h) {
      #pragma unroll
      for (int j = 0; j < 8; ++j) {
        scA[h][j] = coef[h * 32 + g * 8 + j];
        shA[h][j] = coef[64 + h * 32 + g * 8 + j];
      }
    }
  }

  float ps[4] = {0.f, 0.f, 0.f, 0.f};
  float pq[4] = {0.f, 0.f, 0.f, 0.f};

  int nw = gridDim.x * 4;
  for (int tile = blockIdx.x * 4 + w; tile < ntiles; tile += nw) {
    int r0 = tile * 16 + l15;
    uint4 a[4];
    if (r0 < n) {
      const uint4* pa0 = reinterpret_cast<const uint4*>(A0 + (size_t)r0 * 64);
      const uint4* pa1 = reinterpret_cast<const uint4*>(A1 + (size_t)r0 * 64);
      a[0] = pa0[g]; a[1] = pa0[4 + g]; a[2] = pa1[g]; a[3] = pa1[4 + g];
    } else {
      a[0] = a[1] = a[2] = a[3] = make_uint4(0u, 0u, 0u, 0u);
    }
    if (BN) {
      #pragma unroll
      for (int h = 0; h < 2; ++h) {
        uint4 u = a[h];
        float v0 = BFLO(u.x), v1 = BFHI(u.x), v2 = BFLO(u.y), v3 = BFHI(u.y);
        float v4 = BFLO(u.z), v5 = BFHI(u.z), v6 = BFLO(u.w), v7 = BFHI(u.w);
        v0 = v0 * scA[h][0] + shA[h][0]; v0 = v0 > 0.f ? v0 : SLOPE * v0;
        v1 = v1 * scA[h][1] + shA[h][1]; v1 = v1 > 0.f ? v1 : SLOPE * v1;
        v2 = v2 * scA[h][2] + shA[h][2]; v2 = v2 > 0.f ? v2 : SLOPE * v2;
        v3 = v3 * scA[h][3] + shA[h][3]; v3 = v3 > 0.f ? v3 : SLOPE * v3;
        v4 = v4 * scA[h][4] + shA[h][4]; v4 = v4 > 0.f ? v4 : SLOPE * v4;
        v5 = v5 * scA[h][5] + shA[h][5]; v5 = v5 > 0.f ? v5 : SLOPE * v5;
        v6 = v6 * scA[h][6] + shA[h][6]; v6 = v6 > 0.f ? v6 : SLOPE * v6;
        v7 = v7 * scA[h][7] + shA[h][7]; v7 = v7 > 0.f ? v7 : SLOPE * v7;
        uint4 r;
        r.x = (unsigned)f2bf(v0) | ((unsigned)f2bf(v1) << 16);
        r.y = (unsigned)f2bf(v2) | ((unsigned)f2bf(v3) << 16);
        r.z = (unsigned)f2bf(v4) | ((unsigned)f2bf(v5) << 16);
        r.w = (unsigned)f2bf(v6) | ((unsigned)f2bf(v7) << 16);
        a[h] = r;
      }
    }
    f32x4 acc[4] = {};
    #pragma unroll
    for (int s = 0; s < 4; ++s) {
      bf16x8 af = *reinterpret_cast<bf16x8*>(&a[s]);
      #pragma unroll
      for (int t = 0; t < 4; ++t)
        acc[t] = __builtin_amdgcn_mfma_f32_16x16x32_bf16(af, B[t][s], acc[t], 0, 0, 0);
    }
    #pragma unroll
    for (int t = 0; t < 4; ++t) {
      #pragma unroll
      for (int i = 0; i < 4; ++i) {
        int gr = tile * 16 + g * 4 + i;
        if (gr < n) {
          float v = acc[t][i] + bv[t];
          zb[(size_t)gr * 64 + t * 16 + l15] = f2bf(v);
          ps[t] += v;
          pq[t] += v * v;
        }
      }
    }
  }

  #pragma unroll
  for (int t = 0; t < 4; ++t) {
    ps[t] += __shfl_xor(ps[t], 16); ps[t] += __shfl_xor(ps[t], 32);
    pq[t] += __shfl_xor(pq[t], 16); pq[t] += __shfl_xor(pq[t], 32);
  }
  __shared__ float sred[128];
  if (tid < 128) sred[tid] = 0.f;
  __syncthreads();
  if (lane < 16) {
    #pragma unroll
    for (int t = 0; t < 4; ++t) {
      atomicAdd(&sred[t * 16 + l15], ps[t]);
      atomicAdd(&sred[64 + t * 16 + l15], pq[t]);
    }
  }
  __syncthreads();
  if (tid < 128) partial[(size_t)blockIdx.x * 128 + tid] = sred[tid];
}

// reduce partials -> BN coefficients sc/sh directly.  grid = 64
__global__ __launch_bounds__(256) void reduce_coef(
    const float* __restrict__ partial, const float* __restrict__ gamma,
    const float* __restrict__ beta, float* __restrict__ coef, int nblk, float invN) {
  int f = blockIdx.x;
  float s = 0.f, q = 0.f;
  for (int j = threadIdx.x; j < nblk; j += 256) {
    s += partial[(size_t)j * 128 + f];
    q += partial[(size_t)j * 128 + 64 + f];
  }
  #pragma unroll
  for (int o = 1; o < 64; o <<= 1) {
    s += __shfl_xor(s, o);
    q += __shfl_xor(q, o);
  }
  __shared__ float rs[4], rq[4];
  if ((threadIdx.x & 63) == 0) {
    rs[threadIdx.x >> 6] = s;
    rq[threadIdx.x >> 6] = q;
  }
  __syncthreads();
  if (threadIdx.x == 0) {
    float S = rs[0] + rs[1] + rs[2] + rs[3];
    float Q = rq[0] + rq[1] + rq[2] + rq[3];
    float mu = S * invN;
    float var = Q * invN - mu * mu;
    float sc = rsqrtf(var + EPS) * gamma[f];
    coef[f] = sc;
    coef[64 + f] = beta[f] - mu * sc;
  }
}

// ---------------- final BN (apply) + leaky relu -> f32 out ----------------

__global__ void bn_f32_kernel(const unsigned short* __restrict__ zb,
                              const float* __restrict__ coef,
                              float* __restrict__ out, int n) {
  __shared__ float sc[64];
  __shared__ float sh[64];
  if (threadIdx.x < 64) {
    sc[threadIdx.x] = coef[threadIdx.x];
    sh[threadIdx.x] = coef[64 + threadIdx.x];
  }
  __syncthreads();
  int total = n * 16;
  int stride = gridDim.x * blockDim.x;
  for (int idx = blockIdx.x * blockDim.x + threadIdx.x; idx < total; idx += stride) {
    int f0 = (idx & 15) * 4;
    uint2 u = reinterpret_cast<const uint2*>(zb)[idx];
    float4 o;
    float t;
    t = BFLO(u.x) * sc[f0 + 0] + sh[f0 + 0]; o.x = t > 0.f ? t : SLOPE * t;
    t = BFHI(u.x) * sc[f0 + 1] + sh[f0 + 1]; o.y = t > 0.f ? t : SLOPE * t;
    t = BFLO(u.y) * sc[f0 + 2] + sh[f0 + 2]; o.z = t > 0.f ? t : SLOPE * t;
    t = BFHI(u.y) * sc[f0 + 3] + sh[f0 + 3]; o.w = t > 0.f ? t : SLOPE * t;
    reinterpret_cast<float4*>(out)[idx] = o;
  }
}

// ---------------- launch ----------------

extern "C" void kernel_launch(void* const* d_in, const int* in_sizes, int n_in,
                              void* d_out, int out_size, void* d_ws, size_t ws_size,
                              hipStream_t stream) {
  const float* x  = (const float*)d_in[0];
  const int* ei   = (const int*)d_in[1];
  const float* Ws1 = (const float*)d_in[2];
  const float* Wn1 = (const float*)d_in[3];
  const float* b1  = (const float*)d_in[4];
  const float* g1  = (const float*)d_in[5];
  const float* be1 = (const float*)d_in[6];
  const float* Ws2 = (const float*)d_in[7];
  const float* Wn2 = (const float*)d_in[8];
  const float* b2  = (const float*)d_in[9];
  const float* g2  = (const float*)d_in[10];
  const float* be2 = (const float*)d_in[11];
  float* out = (float*)d_out;

  int N = in_sizes[0] / 64;
  int E = in_sizes[1] / 2;
  const int* src = ei;
  const int* dst = ei + E;

  int NB = (N + 255) >> 8;      // buckets of 256 nodes
  const int NBLKB = 256;        // hist/scatter parallel blocks (MUST stay 256)
  int M = NB * NBLKB;

  int ntiles = (N + 15) / 16;
  int gblk = (ntiles + 7) / 8;

  char* ws = (char*)d_ws;
  float* coef1 = (float*)ws;             // 128 (sc|sh, overwritten each call)
  float* coef2 = coef1 + 128;            // 128
  size_t off = 1024;
  auto take = [&](size_t bytes) {
    void* p = ws + off;
    off = (off + bytes + 255) & ~(size_t)255;
    return p;
  };
  int* hist   = (int*)take((size_t)M * 4);
  int* bsum   = (int*)take(512 * 4);
  int* rowptr = (int*)take((size_t)(N + 1) * 4);
  unsigned* binned = (unsigned*)take((size_t)E * 4);
  int* col    = (int*)take((size_t)E * 4);
  unsigned short* xb  = (unsigned short*)take((size_t)N * 64 * 2);
  unsigned short* hmb = (unsigned short*)take((size_t)N * 64 * 2);
  unsigned short* zb  = (unsigned short*)take((size_t)N * 64 * 2);
  float* partial = (float*)take((size_t)gblk * 128 * 4);

  // CSR build + cvt (fused)
  hist_cvt_kernel<<<NBLKB + 128, 1024, NB * 4, stream>>>(dst, hist, E, NB, NBLKB,
                                                         x, xb, N * 16);
  int nb1 = (M + 255) / 256;  // == NB, one scan chunk per bucket
  scan_blk<<<nb1, 256, 0, stream>>>(hist, hist, bsum, M);
  scan_top<<<1, 512, 0, stream>>>(bsum, nb1);
  scatter_kernel<<<NBLKB, 1024, NB * 4, stream>>>(src, dst, hist, bsum, binned, E, NB);
  fine_kernel<<<NB, 256, 0, stream>>>(binned, hist, bsum, rowptr, col, E, NB, NBLKB, N);

  int ab = (N * 8 + 255) / 256;  // 32 nodes per 256-thread block
  float invN = 1.0f / (float)N;

  // layer 1: agg + gemm on raw bf16 x; z kept as bf16 in zb
  agg_kernel<false><<<ab, 256, 0, stream>>>(xb, rowptr, col, nullptr, hmb, N);
  gemm_stream<false><<<gblk, 256, 0, stream>>>(xb, hmb, Ws1, Wn1, b1, nullptr,
                                               zb, partial, N, ntiles);
  reduce_coef<<<64, 256, 0, stream>>>(partial, g1, be1, coef1, gblk, invN);

  // layer 2: BN+leaky of layer 1 folded into consumers (no bn pass, no h1 buffer)
  agg_kernel<true><<<ab, 256, 0, stream>>>(zb, rowptr, col, coef1, hmb, N);
  gemm_stream<true><<<gblk, 256, 0, stream>>>(zb, hmb, Ws2, Wn2, b2, coef1,
                                              zb, partial, N, ntiles);
  reduce_coef<<<64, 256, 0, stream>>>(partial, g2, be2, coef2, gblk, invN);
  bn_f32_kernel<<<2048, 256, 0, stream>>>(zb, coef2, out, N);
}

// Round 12
// 180.912 us; speedup vs baseline: 1.3506x; 1.0084x over previous
//
#include <hip/hip_runtime.h>

#define EPS 1e-5f
#define SLOPE 0.01f

typedef short bf16x8 __attribute__((ext_vector_type(8)));
typedef float f32x4 __attribute__((ext_vector_type(4)));

static __device__ __forceinline__ unsigned short f2bf(float f) {
  unsigned u = __float_as_uint(f);
  unsigned r = (u + 0x7FFFu + ((u >> 16) & 1u)) >> 16;
  return (unsigned short)r;
}
#define BFLO(u) __uint_as_float((u) << 16)
#define BFHI(u) __uint_as_float((u) & 0xFFFF0000u)

// ================= CSR build: two-level counting sort =================
// bucket = dst >> 8 (256 nodes/bucket). hist fused with f32->bf16 cvt.
// NBLKB == 256 so hist chunk index == bucket index (bsum[b] folding).

__global__ __launch_bounds__(1024) void hist_cvt_kernel(
    const int* __restrict__ dst, int* __restrict__ hist, int E, int NB,
    int histBlocks, const float* __restrict__ x, unsigned short* __restrict__ xb,
    int total4) {
  extern __shared__ int lh[];
  if ((int)blockIdx.x < histBlocks) {
    for (int i = threadIdx.x; i < NB; i += blockDim.x) lh[i] = 0;
    __syncthreads();
    int E4 = E >> 2;
    int stride = histBlocks * blockDim.x;
    const int4* d4 = (const int4*)dst;
    for (int i = blockIdx.x * blockDim.x + threadIdx.x; i < E4; i += stride) {
      int4 d = d4[i];
      atomicAdd(&lh[((unsigned)d.x) >> 8], 1);
      atomicAdd(&lh[((unsigned)d.y) >> 8], 1);
      atomicAdd(&lh[((unsigned)d.z) >> 8], 1);
      atomicAdd(&lh[((unsigned)d.w) >> 8], 1);
    }
    if (blockIdx.x == 0) {
      for (int i = (E4 << 2) + threadIdx.x; i < E; i += blockDim.x)
        atomicAdd(&lh[((unsigned)dst[i]) >> 8], 1);
    }
    __syncthreads();
    for (int b = threadIdx.x; b < NB; b += blockDim.x)
      hist[(size_t)b * histBlocks + blockIdx.x] = lh[b];
  } else {
    int cb = blockIdx.x - histBlocks;
    int stride = (gridDim.x - histBlocks) * blockDim.x;
    for (int i = cb * blockDim.x + threadIdx.x; i < total4; i += stride) {
      float4 v = reinterpret_cast<const float4*>(x)[i];
      ushort4 o;
      o.x = f2bf(v.x); o.y = f2bf(v.y); o.z = f2bf(v.z); o.w = f2bf(v.w);
      reinterpret_cast<ushort4*>(xb)[i] = o;
    }
  }
}

__global__ void scan_blk(const int* in, int* out, int* bsum, int n) {
  __shared__ int s[256];
  int i = blockIdx.x * 256 + threadIdx.x;
  int v = (i < n) ? in[i] : 0;
  s[threadIdx.x] = v;
  __syncthreads();
  for (int off = 1; off < 256; off <<= 1) {
    int t = (threadIdx.x >= off) ? s[threadIdx.x - off] : 0;
    __syncthreads();
    s[threadIdx.x] += t;
    __syncthreads();
  }
  if (i < n) out[i] = s[threadIdx.x] - v;
  if (threadIdx.x == 255) bsum[blockIdx.x] = s[255];
}

__global__ void scan_top(int* bsum, int nb) {
  __shared__ int s[512];
  int tid = threadIdx.x;
  int v = (tid < nb) ? bsum[tid] : 0;
  s[tid] = v;
  __syncthreads();
  for (int off = 1; off < 512; off <<= 1) {
    int t = (tid >= off) ? s[tid - off] : 0;
    __syncthreads();
    s[tid] += t;
    __syncthreads();
  }
  if (tid < nb) bsum[tid] = s[tid] - v;
}

// scatter: histS[b*256+blk] + bsum[b] = global base of this block's segment of bucket b
__global__ __launch_bounds__(1024) void scatter_kernel(
    const int* __restrict__ src, const int* __restrict__ dst,
    const int* __restrict__ histS, const int* __restrict__ bsum,
    unsigned* __restrict__ binned, int E, int NB) {
  extern __shared__ int cur[];
  for (int b = threadIdx.x; b < NB; b += blockDim.x)
    cur[b] = histS[(size_t)b * gridDim.x + blockIdx.x] + bsum[b];
  __syncthreads();
  int E4 = E >> 2;
  int stride = gridDim.x * blockDim.x;
  const int4* d4 = (const int4*)dst;
  const int4* s4 = (const int4*)src;
  for (int i = blockIdx.x * blockDim.x + threadIdx.x; i < E4; i += stride) {
    int4 d = d4[i];
    int4 s = s4[i];
    int b0 = ((unsigned)d.x) >> 8;
    binned[atomicAdd(&cur[b0], 1)] = (unsigned)s.x | (((unsigned)d.x & 255u) << 20);
    int b1 = ((unsigned)d.y) >> 8;
    binned[atomicAdd(&cur[b1], 1)] = (unsigned)s.y | (((unsigned)d.y & 255u) << 20);
    int b2 = ((unsigned)d.z) >> 8;
    binned[atomicAdd(&cur[b2], 1)] = (unsigned)s.z | (((unsigned)d.z & 255u) << 20);
    int b3 = ((unsigned)d.w) >> 8;
    binned[atomicAdd(&cur[b3], 1)] = (unsigned)s.w | (((unsigned)d.w & 255u) << 20);
  }
  if (blockIdx.x == 0) {
    for (int i = (E4 << 2) + threadIdx.x; i < E; i += blockDim.x) {
      int d = dst[i];
      int b = ((unsigned)d) >> 8;
      binned[atomicAdd(&cur[b], 1)] = (unsigned)src[i] | (((unsigned)d & 255u) << 20);
    }
  }
}

__global__ __launch_bounds__(256) void fine_kernel(
    const unsigned* __restrict__ binned, const int* __restrict__ histS,
    const int* __restrict__ bsum,
    int* __restrict__ rowptr, int* __restrict__ col, int E, int NB, int NBLKB, int N) {
  __shared__ int ldeg[256];
  __shared__ int lcur[256];
  __shared__ int ss[256];
  int b = blockIdx.x;
  int tid = threadIdx.x;
  int seg_s = histS[(size_t)b * NBLKB] + bsum[b];
  int seg_e = (b + 1 < NB) ? (histS[(size_t)(b + 1) * NBLKB] + bsum[b + 1]) : E;
  ldeg[tid] = 0;
  __syncthreads();
  for (int i = seg_s + tid; i < seg_e; i += 256)
    atomicAdd(&ldeg[(binned[i] >> 20) & 255u], 1);
  __syncthreads();
  int d = ldeg[tid];
  ss[tid] = d;
  __syncthreads();
  for (int off = 1; off < 256; off <<= 1) {
    int t = (tid >= off) ? ss[tid - off] : 0;
    __syncthreads();
    ss[tid] += t;
    __syncthreads();
  }
  int base = seg_s + ss[tid] - d;
  lcur[tid] = base;
  int node = (b << 8) + tid;
  if (node < N) rowptr[node] = base;
  if (b == NB - 1 && tid == 0) rowptr[N] = E;  // sentinel
  __syncthreads();
  for (int i = seg_s + tid; i < seg_e; i += 256) {
    unsigned v = binned[i];
    int pos = atomicAdd(&lcur[(v >> 20) & 255u], 1);
    col[pos] = (int)(v & 0xFFFFFu);
  }
}

// ------- neighbor mean: 8 threads/node, uint4 gathers, unroll-4 -------
// BN=true: apply y = leaky(sc[f]*v + sh[f]) per gathered element.
// NOTE: plain __launch_bounds__(256) — round 11's (256,8) clamped VGPR to 32
// and spilled (+18MB scratch writes, agg 22->42us). Let the compiler pick;
// round 9 chose ~40 VGPR = 8 waves/SIMD.

template <bool BN>
__global__ __launch_bounds__(256) void agg_kernel(
    const unsigned short* __restrict__ hb, const int* __restrict__ rowptr,
    const int* __restrict__ col, const float* __restrict__ coef,
    unsigned short* __restrict__ hm, int n) {
  int t = blockIdx.x * 256 + threadIdx.x;
  int node = t >> 3;
  int fo = (t & 7) * 8;  // 8 features per lane
  if (node >= n) return;
  float scr[8], shr[8];
  if (BN) {
    #pragma unroll
    for (int j = 0; j < 8; ++j) {
      scr[j] = coef[fo + j];
      shr[j] = coef[64 + fo + j];
    }
  }
  int beg = rowptr[node];
  int end = rowptr[node + 1];
  float s0 = 0.f, s1 = 0.f, s2 = 0.f, s3 = 0.f;
  float s4 = 0.f, s5 = 0.f, s6 = 0.f, s7 = 0.f;
  auto acc1 = [&](uint4 u) {
    float v0 = BFLO(u.x), v1 = BFHI(u.x), v2 = BFLO(u.y), v3 = BFHI(u.y);
    float v4 = BFLO(u.z), v5 = BFHI(u.z), v6 = BFLO(u.w), v7 = BFHI(u.w);
    if (BN) {
      v0 = v0 * scr[0] + shr[0]; v0 = v0 > 0.f ? v0 : SLOPE * v0;
      v1 = v1 * scr[1] + shr[1]; v1 = v1 > 0.f ? v1 : SLOPE * v1;
      v2 = v2 * scr[2] + shr[2]; v2 = v2 > 0.f ? v2 : SLOPE * v2;
      v3 = v3 * scr[3] + shr[3]; v3 = v3 > 0.f ? v3 : SLOPE * v3;
      v4 = v4 * scr[4] + shr[4]; v4 = v4 > 0.f ? v4 : SLOPE * v4;
      v5 = v5 * scr[5] + shr[5]; v5 = v5 > 0.f ? v5 : SLOPE * v5;
      v6 = v6 * scr[6] + shr[6]; v6 = v6 > 0.f ? v6 : SLOPE * v6;
      v7 = v7 * scr[7] + shr[7]; v7 = v7 > 0.f ? v7 : SLOPE * v7;
    }
    s0 += v0; s1 += v1; s2 += v2; s3 += v3;
    s4 += v4; s5 += v5; s6 += v6; s7 += v7;
  };
  int e = beg;
  for (; e + 4 <= end; e += 4) {
    int i0 = col[e], i1 = col[e + 1], i2 = col[e + 2], i3 = col[e + 3];
    uint4 u0 = *reinterpret_cast<const uint4*>(&hb[(size_t)i0 * 64 + fo]);
    uint4 u1 = *reinterpret_cast<const uint4*>(&hb[(size_t)i1 * 64 + fo]);
    uint4 u2 = *reinterpret_cast<const uint4*>(&hb[(size_t)i2 * 64 + fo]);
    uint4 u3 = *reinterpret_cast<const uint4*>(&hb[(size_t)i3 * 64 + fo]);
    acc1(u0); acc1(u1); acc1(u2); acc1(u3);
  }
  for (; e < end; ++e) {
    uint4 u = *reinterpret_cast<const uint4*>(&hb[(size_t)col[e] * 64 + fo]);
    acc1(u);
  }
  int deg = end - beg;
  float inv = 1.0f / (float)(deg > 0 ? deg : 1);
  uint4 o;
  o.x = (unsigned)f2bf(s0 * inv) | ((unsigned)f2bf(s1 * inv) << 16);
  o.y = (unsigned)f2bf(s2 * inv) | ((unsigned)f2bf(s3 * inv) << 16);
  o.z = (unsigned)f2bf(s4 * inv) | ((unsigned)f2bf(s5 * inv) << 16);
  o.w = (unsigned)f2bf(s6 * inv) | ((unsigned)f2bf(s7 * inv) << 16);
  *reinterpret_cast<uint4*>(&hm[(size_t)node * 64 + fo]) = o;
}

// ========== streaming MFMA GEMM, bf16 z output ==========
// BN=true: A0 rows come from zb with leaky(sc*v+sh) applied at frag build
// (self-term of layer 2). zb read/write is row-disjoint per wave -> in-place ok.

template <bool BN>
__global__ __launch_bounds__(256) void gemm_stream(
    const unsigned short* __restrict__ A0,
    const unsigned short* __restrict__ A1,
    const float* __restrict__ Wself, const float* __restrict__ Wneigh,
    const float* __restrict__ bias, const float* __restrict__ coef,
    unsigned short* __restrict__ zb, float* __restrict__ partial, int n, int ntiles) {
  int tid = threadIdx.x;
  int lane = tid & 63;
  int w = tid >> 6;
  int l15 = lane & 15;
  int g = lane >> 4;

  bf16x8 B[4][4];
  #pragma unroll
  for (int t = 0; t < 4; ++t) {
    #pragma unroll
    for (int s = 0; s < 4; ++s) {
      const float* base = (s < 2 ? Wself : Wneigh) + (t * 16 + l15) * 64 + (s & 1) * 32 + g * 8;
      float4 w0 = *reinterpret_cast<const float4*>(base);
      float4 w1 = *reinterpret_cast<const float4*>(base + 4);
      bf16x8 b;
      b[0] = (short)f2bf(w0.x); b[1] = (short)f2bf(w0.y);
      b[2] = (short)f2bf(w0.z); b[3] = (short)f2bf(w0.w);
      b[4] = (short)f2bf(w1.x); b[5] = (short)f2bf(w1.y);
      b[6] = (short)f2bf(w1.z); b[7] = (short)f2bf(w1.w);
      B[t][s] = b;
    }
  }
  float bv[4];
  #pragma unroll
  for (int t = 0; t < 4; ++t) bv[t] = bias[t * 16 + l15];

  // per-lane BN coef for A0 frags: features g*8..+7 (k-half 0) and 32+g*8..+7
  float scA[2][8], shA[2][8];
  if (BN) {
    #pragma unroll
    for (int h = 0; h < 2; ++h) {
      #pragma unroll
      for (int j = 0; j < 8; ++j) {
        scA[h][j] = coef[h * 32 + g * 8 + j];
        shA[h][j] = coef[64 + h * 32 + g * 8 + j];
      }
    }
  }

  float ps[4] = {0.f, 0.f, 0.f, 0.f};
  float pq[4] = {0.f, 0.f, 0.f, 0.f};

  int nw = gridDim.x * 4;
  for (int tile = blockIdx.x * 4 + w; tile < ntiles; tile += nw) {
    int r0 = tile * 16 + l15;
    uint4 a[4];
    if (r0 < n) {
      const uint4* pa0 = reinterpret_cast<const uint4*>(A0 + (size_t)r0 * 64);
      const uint4* pa1 = reinterpret_cast<const uint4*>(A1 + (size_t)r0 * 64);
      a[0] = pa0[g]; a[1] = pa0[4 + g]; a[2] = pa1[g]; a[3] = pa1[4 + g];
    } else {
      a[0] = a[1] = a[2] = a[3] = make_uint4(0u, 0u, 0u, 0u);
    }
    if (BN) {
      #pragma unroll
      for (int h = 0; h < 2; ++h) {
        uint4 u = a[h];
        float v0 = BFLO(u.x), v1 = BFHI(u.x), v2 = BFLO(u.y), v3 = BFHI(u.y);
        float v4 = BFLO(u.z), v5 = BFHI(u.z), v6 = BFLO(u.w), v7 = BFHI(u.w);
        v0 = v0 * scA[h][0] + shA[h][0]; v0 = v0 > 0.f ? v0 : SLOPE * v0;
        v1 = v1 * scA[h][1] + shA[h][1]; v1 = v1 > 0.f ? v1 : SLOPE * v1;
        v2 = v2 * scA[h][2] + shA[h][2]; v2 = v2 > 0.f ? v2 : SLOPE * v2;
        v3 = v3 * scA[h][3] + shA[h][3]; v3 = v3 > 0.f ? v3 : SLOPE * v3;
        v4 = v4 * scA[h][4] + shA[h][4]; v4 = v4 > 0.f ? v4 : SLOPE * v4;
        v5 = v5 * scA[h][5] + shA[h][5]; v5 = v5 > 0.f ? v5 : SLOPE * v5;
        v6 = v6 * scA[h][6] + shA[h][6]; v6 = v6 > 0.f ? v6 : SLOPE * v6;
        v7 = v7 * scA[h][7] + shA[h][7]; v7 = v7 > 0.f ? v7 : SLOPE * v7;
        uint4 r;
        r.x = (unsigned)f2bf(v0) | ((unsigned)f2bf(v1) << 16);
        r.y = (unsigned)f2bf(v2) | ((unsigned)f2bf(v3) << 16);
        r.z = (unsigned)f2bf(v4) | ((unsigned)f2bf(v5) << 16);
        r.w = (unsigned)f2bf(v6) | ((unsigned)f2bf(v7) << 16);
        a[h] = r;
      }
    }
    f32x4 acc[4] = {};
    #pragma unroll
    for (int s = 0; s < 4; ++s) {
      bf16x8 af = *reinterpret_cast<bf16x8*>(&a[s]);
      #pragma unroll
      for (int t = 0; t < 4; ++t)
        acc[t] = __builtin_amdgcn_mfma_f32_16x16x32_bf16(af, B[t][s], acc[t], 0, 0, 0);
    }
    #pragma unroll
    for (int t = 0; t < 4; ++t) {
      #pragma unroll
      for (int i = 0; i < 4; ++i) {
        int gr = tile * 16 + g * 4 + i;
        if (gr < n) {
          float v = acc[t][i] + bv[t];
          zb[(size_t)gr * 64 + t * 16 + l15] = f2bf(v);
          ps[t] += v;
          pq[t] += v * v;
        }
      }
    }
  }

  #pragma unroll
  for (int t = 0; t < 4; ++t) {
    ps[t] += __shfl_xor(ps[t], 16); ps[t] += __shfl_xor(ps[t], 32);
    pq[t] += __shfl_xor(pq[t], 16); pq[t] += __shfl_xor(pq[t], 32);
  }
  __shared__ float sred[128];
  if (tid < 128) sred[tid] = 0.f;
  __syncthreads();
  if (lane < 16) {
    #pragma unroll
    for (int t = 0; t < 4; ++t) {
      atomicAdd(&sred[t * 16 + l15], ps[t]);
      atomicAdd(&sred[64 + t * 16 + l15], pq[t]);
    }
  }
  __syncthreads();
  if (tid < 128) partial[(size_t)blockIdx.x * 128 + tid] = sred[tid];
}

// reduce partials -> BN coefficients sc/sh directly.  grid = 64
__global__ __launch_bounds__(256) void reduce_coef(
    const float* __restrict__ partial, const float* __restrict__ gamma,
    const float* __restrict__ beta, float* __restrict__ coef, int nblk, float invN) {
  int f = blockIdx.x;
  float s = 0.f, q = 0.f;
  for (int j = threadIdx.x; j < nblk; j += 256) {
    s += partial[(size_t)j * 128 + f];
    q += partial[(size_t)j * 128 + 64 + f];
  }
  #pragma unroll
  for (int o = 1; o < 64; o <<= 1) {
    s += __shfl_xor(s, o);
    q += __shfl_xor(q, o);
  }
  __shared__ float rs[4], rq[4];
  if ((threadIdx.x & 63) == 0) {
    rs[threadIdx.x >> 6] = s;
    rq[threadIdx.x >> 6] = q;
  }
  __syncthreads();
  if (threadIdx.x == 0) {
    float S = rs[0] + rs[1] + rs[2] + rs[3];
    float Q = rq[0] + rq[1] + rq[2] + rq[3];
    float mu = S * invN;
    float var = Q * invN - mu * mu;
    float sc = rsqrtf(var + EPS) * gamma[f];
    coef[f] = sc;
    coef[64 + f] = beta[f] - mu * sc;
  }
}

// ---------------- final BN (apply) + leaky relu -> f32 out ----------------

__global__ void bn_f32_kernel(const unsigned short* __restrict__ zb,
                              const float* __restrict__ coef,
                              float* __restrict__ out, int n) {
  __shared__ float sc[64];
  __shared__ float sh[64];
  if (threadIdx.x < 64) {
    sc[threadIdx.x] = coef[threadIdx.x];
    sh[threadIdx.x] = coef[64 + threadIdx.x];
  }
  __syncthreads();
  int total = n * 16;
  int stride = gridDim.x * blockDim.x;
  for (int idx = blockIdx.x * blockDim.x + threadIdx.x; idx < total; idx += stride) {
    int f0 = (idx & 15) * 4;
    uint2 u = reinterpret_cast<const uint2*>(zb)[idx];
    float4 o;
    float t;
    t = BFLO(u.x) * sc[f0 + 0] + sh[f0 + 0]; o.x = t > 0.f ? t : SLOPE * t;
    t = BFHI(u.x) * sc[f0 + 1] + sh[f0 + 1]; o.y = t > 0.f ? t : SLOPE * t;
    t = BFLO(u.y) * sc[f0 + 2] + sh[f0 + 2]; o.z = t > 0.f ? t : SLOPE * t;
    t = BFHI(u.y) * sc[f0 + 3] + sh[f0 + 3]; o.w = t > 0.f ? t : SLOPE * t;
    reinterpret_cast<float4*>(out)[idx] = o;
  }
}

// ---------------- launch ----------------

extern "C" void kernel_launch(void* const* d_in, const int* in_sizes, int n_in,
                              void* d_out, int out_size, void* d_ws, size_t ws_size,
                              hipStream_t stream) {
  const float* x  = (const float*)d_in[0];
  const int* ei   = (const int*)d_in[1];
  const float* Ws1 = (const float*)d_in[2];
  const float* Wn1 = (const float*)d_in[3];
  const float* b1  = (const float*)d_in[4];
  const float* g1  = (const float*)d_in[5];
  const float* be1 = (const float*)d_in[6];
  const float* Ws2 = (const float*)d_in[7];
  const float* Wn2 = (const float*)d_in[8];
  const float* b2  = (const float*)d_in[9];
  const float* g2  = (const float*)d_in[10];
  const float* be2 = (const float*)d_in[11];
  float* out = (float*)d_out;

  int N = in_sizes[0] / 64;
  int E = in_sizes[1] / 2;
  const int* src = ei;
  const int* dst = ei + E;

  int NB = (N + 255) >> 8;      // buckets of 256 nodes
  const int NBLKB = 256;        // hist/scatter parallel blocks (MUST stay 256)
  int M = NB * NBLKB;

  int ntiles = (N + 15) / 16;
  int gblk = (ntiles + 7) / 8;

  char* ws = (char*)d_ws;
  float* coef1 = (float*)ws;             // 128 (sc|sh, overwritten each call)
  float* coef2 = coef1 + 128;            // 128
  size_t off = 1024;
  auto take = [&](size_t bytes) {
    void* p = ws + off;
    off = (off + bytes + 255) & ~(size_t)255;
    return p;
  };
  int* hist   = (int*)take((size_t)M * 4);
  int* bsum   = (int*)take(512 * 4);
  int* rowptr = (int*)take((size_t)(N + 1) * 4);
  unsigned* binned = (unsigned*)take((size_t)E * 4);
  int* col    = (int*)take((size_t)E * 4);
  unsigned short* xb  = (unsigned short*)take((size_t)N * 64 * 2);
  unsigned short* hmb = (unsigned short*)take((size_t)N * 64 * 2);
  unsigned short* zb  = (unsigned short*)take((size_t)N * 64 * 2);
  float* partial = (float*)take((size_t)gblk * 128 * 4);

  // CSR build + cvt (fused)
  hist_cvt_kernel<<<NBLKB + 128, 1024, NB * 4, stream>>>(dst, hist, E, NB, NBLKB,
                                                         x, xb, N * 16);
  int nb1 = (M + 255) / 256;  // == NB, one scan chunk per bucket
  scan_blk<<<nb1, 256, 0, stream>>>(hist, hist, bsum, M);
  scan_top<<<1, 512, 0, stream>>>(bsum, nb1);
  scatter_kernel<<<NBLKB, 1024, NB * 4, stream>>>(src, dst, hist, bsum, binned, E, NB);
  fine_kernel<<<NB, 256, 0, stream>>>(binned, hist, bsum, rowptr, col, E, NB, NBLKB, N);

  int ab = (N * 8 + 255) / 256;  // 32 nodes per 256-thread block
  float invN = 1.0f / (float)N;

  // layer 1: agg + gemm on raw bf16 x; z kept as bf16 in zb
  agg_kernel<false><<<ab, 256, 0, stream>>>(xb, rowptr, col, nullptr, hmb, N);
  gemm_stream<false><<<gblk, 256, 0, stream>>>(xb, hmb, Ws1, Wn1, b1, nullptr,
                                               zb, partial, N, ntiles);
  reduce_coef<<<64, 256, 0, stream>>>(partial, g1, be1, coef1, gblk, invN);

  // layer 2: BN+leaky of layer 1 folded into consumers (no bn pass, no h1 buffer)
  agg_kernel<true><<<ab, 256, 0, stream>>>(zb, rowptr, col, coef1, hmb, N);
  gemm_stream<true><<<gblk, 256, 0, stream>>>(zb, hmb, Ws2, Wn2, b2, coef1,
                                              zb, partial, N, ntiles);
  reduce_coef<<<64, 256, 0, stream>>>(partial, g2, be2, coef2, gblk, invN);
  bn_f32_kernel<<<2048, 256, 0, stream>>>(zb, coef2, out, N);
}

// Round 13
// 180.582 us; speedup vs baseline: 1.3531x; 1.0018x over previous
//
#include <hip/hip_runtime.h>

#define EPS 1e-5f
#define SLOPE 0.01f

typedef short bf16x8 __attribute__((ext_vector_type(8)));
typedef float f32x4 __attribute__((ext_vector_type(4)));

static __device__ __forceinline__ unsigned short f2bf(float f) {
  unsigned u = __float_as_uint(f);
  unsigned r = (u + 0x7FFFu + ((u >> 16) & 1u)) >> 16;
  return (unsigned short)r;
}
#define BFLO(u) __uint_as_float((u) << 16)
#define BFHI(u) __uint_as_float((u) & 0xFFFF0000u)

// ================= CSR build: two-level counting sort =================
// bucket = dst >> 8 (256 nodes/bucket). hist fused with f32->bf16 cvt.
// NBLKB == 256 so hist chunk index == bucket index (bsum[b] folding).
// fine_kernel emits a PADDED col: each node's segment 4-aligned and padded
// to a multiple of 4 with index N (a zeroed dummy row) -> agg uses int4
// col loads with no tail/bounds logic.

__global__ __launch_bounds__(1024) void hist_cvt_kernel(
    const int* __restrict__ dst, int* __restrict__ hist, int E, int NB,
    int histBlocks, const float* __restrict__ x, unsigned short* __restrict__ xb,
    int total4) {
  extern __shared__ int lh[];
  if ((int)blockIdx.x < histBlocks) {
    for (int i = threadIdx.x; i < NB; i += blockDim.x) lh[i] = 0;
    __syncthreads();
    int E4 = E >> 2;
    int stride = histBlocks * blockDim.x;
    const int4* d4 = (const int4*)dst;
    for (int i = blockIdx.x * blockDim.x + threadIdx.x; i < E4; i += stride) {
      int4 d = d4[i];
      atomicAdd(&lh[((unsigned)d.x) >> 8], 1);
      atomicAdd(&lh[((unsigned)d.y) >> 8], 1);
      atomicAdd(&lh[((unsigned)d.z) >> 8], 1);
      atomicAdd(&lh[((unsigned)d.w) >> 8], 1);
    }
    if (blockIdx.x == 0) {
      for (int i = (E4 << 2) + threadIdx.x; i < E; i += blockDim.x)
        atomicAdd(&lh[((unsigned)dst[i]) >> 8], 1);
    }
    __syncthreads();
    for (int b = threadIdx.x; b < NB; b += blockDim.x)
      hist[(size_t)b * histBlocks + blockIdx.x] = lh[b];
  } else {
    int cb = blockIdx.x - histBlocks;
    int stride = (gridDim.x - histBlocks) * blockDim.x;
    for (int i = cb * blockDim.x + threadIdx.x; i < total4; i += stride) {
      float4 v = reinterpret_cast<const float4*>(x)[i];
      ushort4 o;
      o.x = f2bf(v.x); o.y = f2bf(v.y); o.z = f2bf(v.z); o.w = f2bf(v.w);
      reinterpret_cast<ushort4*>(xb)[i] = o;
    }
  }
}

__global__ void scan_blk(const int* in, int* out, int* bsum, int n) {
  __shared__ int s[256];
  int i = blockIdx.x * 256 + threadIdx.x;
  int v = (i < n) ? in[i] : 0;
  s[threadIdx.x] = v;
  __syncthreads();
  for (int off = 1; off < 256; off <<= 1) {
    int t = (threadIdx.x >= off) ? s[threadIdx.x - off] : 0;
    __syncthreads();
    s[threadIdx.x] += t;
    __syncthreads();
  }
  if (i < n) out[i] = s[threadIdx.x] - v;
  if (threadIdx.x == 255) bsum[blockIdx.x] = s[255];
}

__global__ void scan_top(int* bsum, int nb) {
  __shared__ int s[512];
  int tid = threadIdx.x;
  int v = (tid < nb) ? bsum[tid] : 0;
  s[tid] = v;
  __syncthreads();
  for (int off = 1; off < 512; off <<= 1) {
    int t = (tid >= off) ? s[tid - off] : 0;
    __syncthreads();
    s[tid] += t;
    __syncthreads();
  }
  if (tid < nb) bsum[tid] = s[tid] - v;
}

// scatter: histS[b*256+blk] + bsum[b] = global base of this block's segment of bucket b
__global__ __launch_bounds__(1024) void scatter_kernel(
    const int* __restrict__ src, const int* __restrict__ dst,
    const int* __restrict__ histS, const int* __restrict__ bsum,
    unsigned* __restrict__ binned, int E, int NB) {
  extern __shared__ int cur[];
  for (int b = threadIdx.x; b < NB; b += blockDim.x)
    cur[b] = histS[(size_t)b * gridDim.x + blockIdx.x] + bsum[b];
  __syncthreads();
  int E4 = E >> 2;
  int stride = gridDim.x * blockDim.x;
  const int4* d4 = (const int4*)dst;
  const int4* s4 = (const int4*)src;
  for (int i = blockIdx.x * blockDim.x + threadIdx.x; i < E4; i += stride) {
    int4 d = d4[i];
    int4 s = s4[i];
    int b0 = ((unsigned)d.x) >> 8;
    binned[atomicAdd(&cur[b0], 1)] = (unsigned)s.x | (((unsigned)d.x & 255u) << 20);
    int b1 = ((unsigned)d.y) >> 8;
    binned[atomicAdd(&cur[b1], 1)] = (unsigned)s.y | (((unsigned)d.y & 255u) << 20);
    int b2 = ((unsigned)d.z) >> 8;
    binned[atomicAdd(&cur[b2], 1)] = (unsigned)s.z | (((unsigned)d.z & 255u) << 20);
    int b3 = ((unsigned)d.w) >> 8;
    binned[atomicAdd(&cur[b3], 1)] = (unsigned)s.w | (((unsigned)d.w & 255u) << 20);
  }
  if (blockIdx.x == 0) {
    for (int i = (E4 << 2) + threadIdx.x; i < E; i += blockDim.x) {
      int d = dst[i];
      int b = ((unsigned)d) >> 8;
      binned[atomicAdd(&cur[b], 1)] = (unsigned)src[i] | (((unsigned)d & 255u) << 20);
    }
  }
}

// fine: per-bucket padded CSR. Bucket b's padded region starts at
// (seg_s + b*1024 + 3)&~3 (1024 slack > max pad growth 768+3 -> no overlap).
// Writes degarr[node] (true degree) and pptr[node] (4-aligned start).
__global__ __launch_bounds__(256) void fine_kernel(
    const unsigned* __restrict__ binned, const int* __restrict__ histS,
    const int* __restrict__ bsum,
    int* __restrict__ degarr, int* __restrict__ pptr, int* __restrict__ col,
    int E, int NB, int NBLKB, int N) {
  __shared__ int ldeg[256];
  __shared__ int lcur[256];
  __shared__ int ss[256];
  int b = blockIdx.x;
  int tid = threadIdx.x;
  int seg_s = histS[(size_t)b * NBLKB] + bsum[b];
  int seg_e = (b + 1 < NB) ? (histS[(size_t)(b + 1) * NBLKB] + bsum[b + 1]) : E;
  int pbase = (seg_s + b * 1024 + 3) & ~3;
  ldeg[tid] = 0;
  __syncthreads();
  for (int i = seg_s + tid; i < seg_e; i += 256)
    atomicAdd(&ldeg[(binned[i] >> 20) & 255u], 1);
  __syncthreads();
  int d = ldeg[tid];
  int pd = (d + 3) & ~3;
  ss[tid] = pd;
  __syncthreads();
  for (int off = 1; off < 256; off <<= 1) {
    int t = (tid >= off) ? ss[tid - off] : 0;
    __syncthreads();
    ss[tid] += t;
    __syncthreads();
  }
  int pstart = pbase + ss[tid] - pd;
  lcur[tid] = pstart;
  int node = (b << 8) + tid;
  if (node < N) {
    degarr[node] = d;
    pptr[node] = pstart;
  }
  __syncthreads();
  for (int i = seg_s + tid; i < seg_e; i += 256) {
    unsigned v = binned[i];
    int pos = atomicAdd(&lcur[(v >> 20) & 255u], 1);
    col[pos] = (int)(v & 0xFFFFFu);
  }
  for (int k = d; k < pd; ++k) col[pstart + k] = N;  // pads -> zero row
}

// ------- neighbor mean: 8 threads/node, int4 col + uint4 gathers -------
// Padded col: no tail loop, no bounds checks. Row N of hb is all-zero.

__global__ __launch_bounds__(256) void agg_kernel(
    const unsigned short* __restrict__ hb, const int* __restrict__ degarr,
    const int* __restrict__ pptr, const int* __restrict__ col,
    unsigned short* __restrict__ hm, int n) {
  int t = blockIdx.x * 256 + threadIdx.x;
  int node = t >> 3;
  int fo = (t & 7) * 8;  // 8 features per lane
  if (node >= n) return;
  int deg = degarr[node];
  const int4* cp = reinterpret_cast<const int4*>(col + pptr[node]);
  int nit = (deg + 3) >> 2;
  float s0 = 0.f, s1 = 0.f, s2 = 0.f, s3 = 0.f;
  float s4 = 0.f, s5 = 0.f, s6 = 0.f, s7 = 0.f;
  for (int it = 0; it < nit; ++it) {
    int4 c = cp[it];
    uint4 u0 = *reinterpret_cast<const uint4*>(&hb[(size_t)c.x * 64 + fo]);
    uint4 u1 = *reinterpret_cast<const uint4*>(&hb[(size_t)c.y * 64 + fo]);
    uint4 u2 = *reinterpret_cast<const uint4*>(&hb[(size_t)c.z * 64 + fo]);
    uint4 u3 = *reinterpret_cast<const uint4*>(&hb[(size_t)c.w * 64 + fo]);
    s0 += BFLO(u0.x) + BFLO(u1.x) + BFLO(u2.x) + BFLO(u3.x);
    s1 += BFHI(u0.x) + BFHI(u1.x) + BFHI(u2.x) + BFHI(u3.x);
    s2 += BFLO(u0.y) + BFLO(u1.y) + BFLO(u2.y) + BFLO(u3.y);
    s3 += BFHI(u0.y) + BFHI(u1.y) + BFHI(u2.y) + BFHI(u3.y);
    s4 += BFLO(u0.z) + BFLO(u1.z) + BFLO(u2.z) + BFLO(u3.z);
    s5 += BFHI(u0.z) + BFHI(u1.z) + BFHI(u2.z) + BFHI(u3.z);
    s6 += BFLO(u0.w) + BFLO(u1.w) + BFLO(u2.w) + BFLO(u3.w);
    s7 += BFHI(u0.w) + BFHI(u1.w) + BFHI(u2.w) + BFHI(u3.w);
  }
  float inv = 1.0f / (float)(deg > 0 ? deg : 1);
  uint4 o;
  o.x = (unsigned)f2bf(s0 * inv) | ((unsigned)f2bf(s1 * inv) << 16);
  o.y = (unsigned)f2bf(s2 * inv) | ((unsigned)f2bf(s3 * inv) << 16);
  o.z = (unsigned)f2bf(s4 * inv) | ((unsigned)f2bf(s5 * inv) << 16);
  o.w = (unsigned)f2bf(s6 * inv) | ((unsigned)f2bf(s7 * inv) << 16);
  *reinterpret_cast<uint4*>(&hm[(size_t)node * 64 + fo]) = o;
}

// ========== streaming MFMA GEMM, bf16 z output (round-9 version) ==========

__global__ __launch_bounds__(256) void gemm_stream(
    const unsigned short* __restrict__ A0,
    const unsigned short* __restrict__ A1,
    const float* __restrict__ Wself, const float* __restrict__ Wneigh,
    const float* __restrict__ bias,
    unsigned short* __restrict__ zb, float* __restrict__ partial, int n, int ntiles) {
  int tid = threadIdx.x;
  int lane = tid & 63;
  int w = tid >> 6;
  int l15 = lane & 15;
  int g = lane >> 4;

  bf16x8 B[4][4];
  #pragma unroll
  for (int t = 0; t < 4; ++t) {
    #pragma unroll
    for (int s = 0; s < 4; ++s) {
      const float* base = (s < 2 ? Wself : Wneigh) + (t * 16 + l15) * 64 + (s & 1) * 32 + g * 8;
      float4 w0 = *reinterpret_cast<const float4*>(base);
      float4 w1 = *reinterpret_cast<const float4*>(base + 4);
      bf16x8 b;
      b[0] = (short)f2bf(w0.x); b[1] = (short)f2bf(w0.y);
      b[2] = (short)f2bf(w0.z); b[3] = (short)f2bf(w0.w);
      b[4] = (short)f2bf(w1.x); b[5] = (short)f2bf(w1.y);
      b[6] = (short)f2bf(w1.z); b[7] = (short)f2bf(w1.w);
      B[t][s] = b;
    }
  }
  float bv[4];
  #pragma unroll
  for (int t = 0; t < 4; ++t) bv[t] = bias[t * 16 + l15];

  float ps[4] = {0.f, 0.f, 0.f, 0.f};
  float pq[4] = {0.f, 0.f, 0.f, 0.f};

  int nw = gridDim.x * 4;
  for (int tile = blockIdx.x * 4 + w; tile < ntiles; tile += nw) {
    int r0 = tile * 16 + l15;
    uint4 a[4];
    if (r0 < n) {
      const uint4* pa0 = reinterpret_cast<const uint4*>(A0 + (size_t)r0 * 64);
      const uint4* pa1 = reinterpret_cast<const uint4*>(A1 + (size_t)r0 * 64);
      a[0] = pa0[g]; a[1] = pa0[4 + g]; a[2] = pa1[g]; a[3] = pa1[4 + g];
    } else {
      a[0] = a[1] = a[2] = a[3] = make_uint4(0u, 0u, 0u, 0u);
    }
    f32x4 acc[4] = {};
    #pragma unroll
    for (int s = 0; s < 4; ++s) {
      bf16x8 af = *reinterpret_cast<bf16x8*>(&a[s]);
      #pragma unroll
      for (int t = 0; t < 4; ++t)
        acc[t] = __builtin_amdgcn_mfma_f32_16x16x32_bf16(af, B[t][s], acc[t], 0, 0, 0);
    }
    #pragma unroll
    for (int t = 0; t < 4; ++t) {
      #pragma unroll
      for (int i = 0; i < 4; ++i) {
        int gr = tile * 16 + g * 4 + i;
        if (gr < n) {
          float v = acc[t][i] + bv[t];
          zb[(size_t)gr * 64 + t * 16 + l15] = f2bf(v);
          ps[t] += v;
          pq[t] += v * v;
        }
      }
    }
  }

  #pragma unroll
  for (int t = 0; t < 4; ++t) {
    ps[t] += __shfl_xor(ps[t], 16); ps[t] += __shfl_xor(ps[t], 32);
    pq[t] += __shfl_xor(pq[t], 16); pq[t] += __shfl_xor(pq[t], 32);
  }
  __shared__ float sred[128];
  if (tid < 128) sred[tid] = 0.f;
  __syncthreads();
  if (lane < 16) {
    #pragma unroll
    for (int t = 0; t < 4; ++t) {
      atomicAdd(&sred[t * 16 + l15], ps[t]);
      atomicAdd(&sred[64 + t * 16 + l15], pq[t]);
    }
  }
  __syncthreads();
  if (tid < 128) partial[(size_t)blockIdx.x * 128 + tid] = sred[tid];
}

// reduce partials -> BN coefficients sc/sh directly.  grid = 64
__global__ __launch_bounds__(256) void reduce_coef(
    const float* __restrict__ partial, const float* __restrict__ gamma,
    const float* __restrict__ beta, float* __restrict__ coef, int nblk, float invN) {
  int f = blockIdx.x;
  float s = 0.f, q = 0.f;
  for (int j = threadIdx.x; j < nblk; j += 256) {
    s += partial[(size_t)j * 128 + f];
    q += partial[(size_t)j * 128 + 64 + f];
  }
  #pragma unroll
  for (int o = 1; o < 64; o <<= 1) {
    s += __shfl_xor(s, o);
    q += __shfl_xor(q, o);
  }
  __shared__ float rs[4], rq[4];
  if ((threadIdx.x & 63) == 0) {
    rs[threadIdx.x >> 6] = s;
    rq[threadIdx.x >> 6] = q;
  }
  __syncthreads();
  if (threadIdx.x == 0) {
    float S = rs[0] + rs[1] + rs[2] + rs[3];
    float Q = rq[0] + rq[1] + rq[2] + rq[3];
    float mu = S * invN;
    float var = Q * invN - mu * mu;
    float sc = rsqrtf(var + EPS) * gamma[f];
    coef[f] = sc;
    coef[64 + f] = beta[f] - mu * sc;
  }
}

// ---------------- BN (apply) + leaky relu ----------------

__global__ void bn_bf16_kernel(const unsigned short* __restrict__ zb,
                               const float* __restrict__ coef,
                               unsigned short* __restrict__ out, int n) {
  __shared__ float sc[64];
  __shared__ float sh[64];
  if (threadIdx.x < 64) {
    sc[threadIdx.x] = coef[threadIdx.x];
    sh[threadIdx.x] = coef[64 + threadIdx.x];
  }
  __syncthreads();
  int total = n * 16;
  int stride = gridDim.x * blockDim.x;
  for (int idx = blockIdx.x * blockDim.x + threadIdx.x; idx < total; idx += stride) {
    int f0 = (idx & 15) * 4;
    uint2 u = reinterpret_cast<const uint2*>(zb)[idx];
    float t;
    ushort4 o;
    t = BFLO(u.x) * sc[f0 + 0] + sh[f0 + 0]; o.x = f2bf(t > 0.f ? t : SLOPE * t);
    t = BFHI(u.x) * sc[f0 + 1] + sh[f0 + 1]; o.y = f2bf(t > 0.f ? t : SLOPE * t);
    t = BFLO(u.y) * sc[f0 + 2] + sh[f0 + 2]; o.z = f2bf(t > 0.f ? t : SLOPE * t);
    t = BFHI(u.y) * sc[f0 + 3] + sh[f0 + 3]; o.w = f2bf(t > 0.f ? t : SLOPE * t);
    reinterpret_cast<ushort4*>(out)[idx] = o;
  }
}

__global__ void bn_f32_kernel(const unsigned short* __restrict__ zb,
                              const float* __restrict__ coef,
                              float* __restrict__ out, int n) {
  __shared__ float sc[64];
  __shared__ float sh[64];
  if (threadIdx.x < 64) {
    sc[threadIdx.x] = coef[threadIdx.x];
    sh[threadIdx.x] = coef[64 + threadIdx.x];
  }
  __syncthreads();
  int total = n * 16;
  int stride = gridDim.x * blockDim.x;
  for (int idx = blockIdx.x * blockDim.x + threadIdx.x; idx < total; idx += stride) {
    int f0 = (idx & 15) * 4;
    uint2 u = reinterpret_cast<const uint2*>(zb)[idx];
    float4 o;
    float t;
    t = BFLO(u.x) * sc[f0 + 0] + sh[f0 + 0]; o.x = t > 0.f ? t : SLOPE * t;
    t = BFHI(u.x) * sc[f0 + 1] + sh[f0 + 1]; o.y = t > 0.f ? t : SLOPE * t;
    t = BFLO(u.y) * sc[f0 + 2] + sh[f0 + 2]; o.z = t > 0.f ? t : SLOPE * t;
    t = BFHI(u.y) * sc[f0 + 3] + sh[f0 + 3]; o.w = t > 0.f ? t : SLOPE * t;
    reinterpret_cast<float4*>(out)[idx] = o;
  }
}

// ---------------- launch ----------------

extern "C" void kernel_launch(void* const* d_in, const int* in_sizes, int n_in,
                              void* d_out, int out_size, void* d_ws, size_t ws_size,
                              hipStream_t stream) {
  const float* x  = (const float*)d_in[0];
  const int* ei   = (const int*)d_in[1];
  const float* Ws1 = (const float*)d_in[2];
  const float* Wn1 = (const float*)d_in[3];
  const float* b1  = (const float*)d_in[4];
  const float* g1  = (const float*)d_in[5];
  const float* be1 = (const float*)d_in[6];
  const float* Ws2 = (const float*)d_in[7];
  const float* Wn2 = (const float*)d_in[8];
  const float* b2  = (const float*)d_in[9];
  const float* g2  = (const float*)d_in[10];
  const float* be2 = (const float*)d_in[11];
  float* out = (float*)d_out;

  int N = in_sizes[0] / 64;
  int E = in_sizes[1] / 2;
  const int* src = ei;
  const int* dst = ei + E;

  int NB = (N + 255) >> 8;      // buckets of 256 nodes
  const int NBLKB = 256;        // hist/scatter parallel blocks (MUST stay 256)
  int M = NB * NBLKB;

  int ntiles = (N + 15) / 16;
  int gblk = (ntiles + 7) / 8;

  char* ws = (char*)d_ws;
  float* coef1 = (float*)ws;             // 128 (sc|sh, overwritten each call)
  float* coef2 = coef1 + 128;            // 128
  size_t off = 1024;
  auto take = [&](size_t bytes) {
    void* p = ws + off;
    off = (off + bytes + 255) & ~(size_t)255;
    return p;
  };
  int* hist   = (int*)take((size_t)M * 4);
  int* bsum   = (int*)take(512 * 4);
  int* degarr = (int*)take((size_t)N * 4);
  int* pptr   = (int*)take((size_t)N * 4);
  unsigned* binned = (unsigned*)take((size_t)E * 4);
  int* col    = (int*)take(((size_t)E + (size_t)NB * 1024 + 1024) * 4);
  unsigned short* xb  = (unsigned short*)take((size_t)(N + 1) * 64 * 2);
  unsigned short* hmb = (unsigned short*)take((size_t)N * 64 * 2);
  unsigned short* h1b = (unsigned short*)take((size_t)(N + 1) * 64 * 2);
  unsigned short* zb  = (unsigned short*)take((size_t)N * 64 * 2);
  float* partial = (float*)take((size_t)gblk * 128 * 4);

  // zero dummy row N of the gather sources (col pads point there)
  hipMemsetAsync(xb + (size_t)N * 64, 0, 128, stream);
  hipMemsetAsync(h1b + (size_t)N * 64, 0, 128, stream);

  // CSR build + cvt (fused)
  hist_cvt_kernel<<<NBLKB + 128, 1024, NB * 4, stream>>>(dst, hist, E, NB, NBLKB,
                                                         x, xb, N * 16);
  int nb1 = (M + 255) / 256;  // == NB, one scan chunk per bucket
  scan_blk<<<nb1, 256, 0, stream>>>(hist, hist, bsum, M);
  scan_top<<<1, 512, 0, stream>>>(bsum, nb1);
  scatter_kernel<<<NBLKB, 1024, NB * 4, stream>>>(src, dst, hist, bsum, binned, E, NB);
  fine_kernel<<<NB, 256, 0, stream>>>(binned, hist, bsum, degarr, pptr, col,
                                      E, NB, NBLKB, N);

  int ab = (N * 8 + 255) / 256;  // 32 nodes per 256-thread block
  float invN = 1.0f / (float)N;

  // layer 1
  agg_kernel<<<ab, 256, 0, stream>>>(xb, degarr, pptr, col, hmb, N);
  gemm_stream<<<gblk, 256, 0, stream>>>(xb, hmb, Ws1, Wn1, b1, zb, partial, N, ntiles);
  reduce_coef<<<64, 256, 0, stream>>>(partial, g1, be1, coef1, gblk, invN);
  bn_bf16_kernel<<<2048, 256, 0, stream>>>(zb, coef1, h1b, N);

  // layer 2
  agg_kernel<<<ab, 256, 0, stream>>>(h1b, degarr, pptr, col, hmb, N);
  gemm_stream<<<gblk, 256, 0, stream>>>(h1b, hmb, Ws2, Wn2, b2, zb, partial, N, ntiles);
  reduce_coef<<<64, 256, 0, stream>>>(partial, g2, be2, coef2, gblk, invN);
  bn_f32_kernel<<<2048, 256, 0, stream>>>(zb, coef2, out, N);
}